// Round 14
// baseline (216.595 us; speedup 1.0000x reference)
//
#include <hip/hip_runtime.h>
#include <stdint.h>

#define THR  1.0f
#define BETA 0.95f
#define SX   4096.0f            // x scale (2^12) -> no fp16 denormal flush
#define SW   512.0f             // W scale (2^9)
#define SINV (1.0f / (4096.0f * 512.0f))
#define W1N  (128 * 784)

typedef __attribute__((ext_vector_type(8)))  _Float16 f16x8;
typedef __attribute__((ext_vector_type(16))) float    f32x16;
typedef __attribute__((ext_vector_type(4)))  float    fvec4;

__device__ __forceinline__ void gll16(const float* g, float* l){
  __builtin_amdgcn_global_load_lds((const __attribute__((address_space(1))) void*)g,
                                   (__attribute__((address_space(3))) void*)l, 16, 0, 0);
}

// 2-term RNE fp16 split of scaled W1 in per-16k fragment order:
// fragment (gks 0..48, nf 0..3, term 0..1) = 512 f16 (1KB); lane (kg*32+r)
// holds 8 f16 for col h=nf*32+r, k=gks*16+kg*8+0..7.
__global__ void split_w1(const float* __restrict__ W1, _Float16* __restrict__ wB){
  int i = blockIdx.x * 256 + threadIdx.x;
  if (i < W1N) {
    int h = i / 784, k = i % 784;
    float v = W1[i] * SW;
    _Float16 hi = (_Float16)v;
    _Float16 lo = (_Float16)(v - (float)hi);
    int ks = k >> 4, kg = (k >> 3) & 1, j = k & 7, nf = h >> 5, r = h & 31;
    int base = ((ks * 4 + nf) * 2) * 512 + (kg * 32 + r) * 8 + j;
    wB[base]       = hi;   // term 0
    wB[base + 512] = lo;   // term 1
  }
}

// cur1[m][h] = sum_k x[m][k]*W1[h][k] + b1[h] (scaled acc; bias in epilogue).
// BARRIER-FREE, wave-decoupled: wave w owns rows w*32..+32 of a 128-row block.
// A: wave-PRIVATE fragment-major LDS, 4-slab rotation (2KB/step), staged via
//    global_load_lds at distance 3 — only this wave reads it -> no barrier.
// B: coalesced 1KB fragment loads straight to registers (L1-broadcast-hot),
//    double-buffered at distance 1.
// One counted vmcnt per step: younger set = A(s+1..s+3) [6] + B(s+1) [8] = 14.
// No s_barrier anywhere -> a slow load stalls one wave, not the whole CU.
__launch_bounds__(256, 2)
__global__ void gemm1(const float* __restrict__ x,
                      const _Float16* __restrict__ wB,
                      const float* __restrict__ b1,
                      float* __restrict__ cur1,
                      long row0){
  __shared__ float lds[8192];             // 4 waves x 4 slabs x 512 floats (32KB)
  const int lane = threadIdx.x & 63;
  const int w    = threadIdx.x >> 6;
  const long blk_row0 = row0 + (long)blockIdx.x * 128;
  const int r  = lane & 31;
  const int kg = lane >> 5;

  const float* xA = x + (blk_row0 + w * 32 + r) * 784 + kg * 8;  // wave's A rows
  const f16x8* wv = (const f16x8*)wB + lane;    // frag f of step s at +((s*8+f)*64)
  float* myl = &lds[w * 2048];                  // wave-private 8KB

  // stage A fragment of 16-k step s into private slab bb (2 x gll16)
  #define AST(bb, s) {                                                       \
    gll16(xA + (s) * 16,     myl + (bb) * 512);                              \
    gll16(xA + (s) * 16 + 4, myl + (bb) * 512 + 256); }

  // load B fragments of step s into an 8 x f16x8 register set (coalesced 1KB each)
  #define LDB(dst, s) { _Pragma("unroll") for (int f = 0; f < 8; ++f)        \
      dst[f] = wv[((s) * 8 + f) * 64]; }

  // counted wait + scheduler pin (no barrier!)
  #define VMW(n) { asm volatile("s_waitcnt vmcnt(" #n ")" ::: "memory");     \
                   __builtin_amdgcn_sched_barrier(0); }

  // consume step s from private slab bb with B regs breg: split + 12 MFMA
  #define CPH(bb, breg) {                                                    \
    fvec4 a0 = *(const fvec4*)(myl + (bb) * 512 + lane * 4);                 \
    fvec4 a1 = *(const fvec4*)(myl + (bb) * 512 + 256 + lane * 4);           \
    f16x8 ah, al;                                                            \
    _Pragma("unroll") for (int j = 0; j < 8; ++j) {                          \
      float v = ((j < 4) ? a0[j] : a1[j - 4]) * SX;                          \
      _Float16 hh = (_Float16)v;                                             \
      ah[j] = hh; al[j] = (_Float16)(v - (float)hh);                         \
    }                                                                        \
    _Pragma("unroll") for (int nf = 0; nf < 4; ++nf) {                       \
      acc[nf] = __builtin_amdgcn_mfma_f32_32x32x16_f16(ah, breg[nf * 2],     acc[nf], 0, 0, 0); \
      acc[nf] = __builtin_amdgcn_mfma_f32_32x32x16_f16(ah, breg[nf * 2 + 1], acc[nf], 0, 0, 0); \
      acc[nf] = __builtin_amdgcn_mfma_f32_32x32x16_f16(al, breg[nf * 2],     acc[nf], 0, 0, 0); \
    } }

  // steady-state step: stage A(s+3), load B(s+1), wait(14), compute s
  #define STEP(s, bc, bn) {                                                  \
    AST((s + 3) & 3, (s) + 3);                                               \
    LDB(bn, (s) + 1);                                                        \
    VMW(14);                                                                 \
    CPH((s) & 3, bc); }

  f32x16 acc[4] = {};
  f16x8 bA[8], bB[8];

  // prologue: A(0..2) staged, B(0) in regs
  AST(0, 0); AST(1, 1); AST(2, 2);
  LDB(bA, 0);

  // main: s = 0..45 (A stages up to slab 48; B loads up to B(46))
  for (int s2 = 0; s2 < 23; ++s2) {
    const int s = 2 * s2;
    STEP(s,     bA, bB);
    STEP(s + 1, bB, bA);
  }
  // s=46: no A left; younger than {A(46),B(46)} = A(47)2 + A(48)2 + B(47)8 = 12
  LDB(bB, 47); VMW(12); CPH(2, bA);
  // s=47: younger = A(48)2 + B(48)8 = 10
  LDB(bA, 48); VMW(10); CPH(3, bB);
  // s=48: nothing outstanding allowed
  VMW(0); CPH(0, bA);

  // C/D layout (m74/m101-verified): col = lane&31, row = (reg&3)+8*(reg>>2)+4*(lane>>5)
  float b1v[4];
  #pragma unroll
  for (int nf = 0; nf < 4; ++nf) b1v[nf] = b1[nf * 32 + r];
  long m0 = (long)blockIdx.x * 128 + w * 32;
  #pragma unroll
  for (int nf = 0; nf < 4; ++nf)
    #pragma unroll
    for (int reg = 0; reg < 16; ++reg) {
      int rr = (reg & 3) + 8 * (reg >> 2) + 4 * kg;
      cur1[(m0 + rr) * 128 + nf * 32 + r] = acc[nf][reg] * SINV + b1v[nf];
    }
  #undef AST
  #undef LDB
  #undef VMW
  #undef CPH
  #undef STEP
}

// LIF recurrence + layer 2 (bias1 already folded into cur1).
__launch_bounds__(256)
__global__ void lif(const float* __restrict__ cur1,
                    const float* __restrict__ W2,
                    const float* __restrict__ b2,
                    float* __restrict__ out,
                    float* __restrict__ state1,
                    float* __restrict__ state2,
                    int t0, int tn){
  const int lane = threadIdx.x & 63;
  const int b = blockIdx.x * 4 + (threadIdx.x >> 6);
  const int o = lane & 15;
  const int c = lane >> 4;

  float wv[32];
  #pragma unroll
  for (int j = 0; j < 32; ++j) wv[j] = 0.f;
  if (o < 10) {
    #pragma unroll
    for (int j = 0; j < 32; ++j) wv[j] = W2[o * 128 + c * 32 + j];
  }
  float b2v = (lane < 10) ? b2[lane] : 0.f;

  float mem1a, mem1b, mem2;
  if (t0 == 0) { mem1a = 0.f; mem1b = 0.f; mem2 = 0.f; }
  else {
    mem1a = state1[b * 128 + lane];
    mem1b = state1[b * 128 + 64 + lane];
    mem2  = (lane < 10) ? state2[b * 10 + lane] : 0.f;
  }

  for (int t = t0; t < tn; ++t) {
    long base = ((long)(t - t0) * 4096 + b) * 128;
    float c1a = cur1[base + lane];
    float c1b = cur1[base + 64 + lane];
    float r1a = (mem1a > THR) ? THR : 0.f;
    float r1b = (mem1b > THR) ? THR : 0.f;
    mem1a = BETA * mem1a + c1a - r1a;
    mem1b = BETA * mem1b + c1b - r1b;

    uint64_t mA = __ballot(mem1a > THR);
    uint64_t mB = __ballot(mem1b > THR);
    uint64_t m64 = (c & 2) ? mB : mA;
    uint32_t bits = (uint32_t)(m64 >> ((c & 1) << 5));

    float s = 0.f;
    #pragma unroll
    for (int j = 0; j < 32; ++j)
      s = fmaf((float)((bits >> j) & 1u), wv[j], s);   // bfe+cvt+fma
    s += __shfl_xor(s, 16);
    s += __shfl_xor(s, 32);

    if (lane < 10) {
      float cur2 = s + b2v;
      float r2 = (mem2 > THR) ? THR : 0.f;
      mem2 = BETA * mem2 + cur2 - r2;
      float s2 = (mem2 > THR) ? 1.f : 0.f;
      long ob = (long)t * 40960 + (long)b * 10 + lane;
      out[ob] = s2;
      out[1228800 + ob] = mem2;
    }
  }

  if (tn < 30) {
    state1[b * 128 + lane] = mem1a;
    state1[b * 128 + 64 + lane] = mem1b;
    if (lane < 10) state2[b * 10 + lane] = mem2;
  }
}

extern "C" void kernel_launch(void* const* d_in, const int* in_sizes, int n_in,
                              void* d_out, int out_size, void* d_ws, size_t ws_size,
                              hipStream_t stream) {
  const float* x  = (const float*)d_in[0];
  const float* W1 = (const float*)d_in[1];
  const float* b1 = (const float*)d_in[2];
  const float* W2 = (const float*)d_in[3];
  const float* b2 = (const float*)d_in[4];
  float* out = (float*)d_out;

  const int T = 30, B = 4096;

  char* ws = (char*)d_ws;
  _Float16* wB = (_Float16*)ws;                  // 49*8*512 fp16 = 392KB
  size_t off = (size_t)49 * 8 * 512 * sizeof(_Float16);
  off = (off + 255) & ~(size_t)255;
  float* state1 = (float*)(ws + off); off += (size_t)B * 128 * 4;
  float* state2 = (float*)(ws + off); off += (size_t)B * 10 * 4;
  off = (off + 255) & ~(size_t)255;
  float* cur1 = (float*)(ws + off);

  size_t per_t = (size_t)B * 128 * 4;
  size_t avail = (ws_size > off) ? (ws_size - off) : 0;
  int CH = (int)(avail / per_t);
  if (CH > T) CH = T;
  if (CH < 1) CH = 1;

  split_w1<<<(W1N + 255) / 256, 256, 0, stream>>>(W1, wB);

  for (int t0 = 0; t0 < T; t0 += CH) {
    int tn = (t0 + CH < T) ? (t0 + CH) : T;
    int mrows = (tn - t0) * B;                   // multiple of 4096 -> multiple of 128
    gemm1<<<mrows / 128, 256, 0, stream>>>(x, wB, b1, cur1, (long)t0 * B);
    lif<<<B / 4, 256, 0, stream>>>(cur1, W2, b2, out, state1, state2, t0, tn);
  }
}

// Round 15
// 153.899 us; speedup vs baseline: 1.4074x; 1.4074x over previous
//
#include <hip/hip_runtime.h>
#include <stdint.h>

#define THR  1.0f
#define BETA 0.95f
#define SX   4096.0f            // x scale (2^12) -> no fp16 denormal flush
#define SW   512.0f             // W scale (2^9)
#define SINV (1.0f / (4096.0f * 512.0f))
#define W1N  (128 * 784)

typedef __attribute__((ext_vector_type(8)))  _Float16 f16x8;
typedef __attribute__((ext_vector_type(16))) float    f32x16;
typedef __attribute__((ext_vector_type(4)))  float    fvec4;

__device__ __forceinline__ void gll16(const float* g, float* l){
  __builtin_amdgcn_global_load_lds((const __attribute__((address_space(1))) void*)g,
                                   (__attribute__((address_space(3))) void*)l, 16, 0, 0);
}

// 2-term RNE fp16 split of scaled W1 in per-16k fragment order:
// fragment (gks 0..48, nf 0..3, term 0..1) = 512 f16 (1KB); lane (kg*32+r)
// holds 8 f16 for col h=nf*32+r, k=gks*16+kg*8+0..7.
__global__ void split_w1(const float* __restrict__ W1, _Float16* __restrict__ wB){
  int i = blockIdx.x * 256 + threadIdx.x;
  if (i < W1N) {
    int h = i / 784, k = i % 784;
    float v = W1[i] * SW;
    _Float16 hi = (_Float16)v;
    _Float16 lo = (_Float16)(v - (float)hi);
    int ks = k >> 4, kg = (k >> 3) & 1, j = k & 7, nf = h >> 5, r = h & 31;
    int base = ((ks * 4 + nf) * 2) * 512 + (kg * 32 + r) * 8 + j;
    wB[base]       = hi;   // term 0
    wB[base + 512] = lo;   // term 1
  }
}

// cur1[m][h] = sum_k x[m][k]*W1[h][k] + b1[h] (scaled acc; bias in epilogue).
// Block: 4 waves, tile 128m x 128n. 25 slabs: s=0..23 are 32-k, s=24 is 16-k.
// A: fragment-major wave-private LDS, 3-buffer rotation (DISTANCE 2).
// B: fragment-major shared LDS, 2-buffer rotation (distance 1, but its
//    in-order vmcnt gate is A(s), issued 2 phases back).
// Phase s: FENCE_A; STAGE_B(s+1); STAGE_A(s+2); vmcnt(12); barrier; CPH(s).
// vmcnt in-order retirement: <=12 outstanding = A(s+1)4 + B(s+1)4 + A(s+2)4
// -> A(s),B(s) confirmed, staged ~2 phase-periods ago => near-zero stall.
// LDS 80KB (A 3x16KB + B 2x16KB) -> 2 blocks/CU.
__launch_bounds__(256, 2)
__global__ void gemm1(const float* __restrict__ x,
                      const float* __restrict__ wBf,   // wB viewed as float*
                      const float* __restrict__ b1,
                      float* __restrict__ cur1,
                      long row0){
  __shared__ float lds[20480];            // A: [0,12288) 3 bufs; B: [12288,20480) 2 bufs
  const int lane = threadIdx.x & 63;
  const int w    = threadIdx.x >> 6;
  const long blk_row0 = row0 + (long)blockIdx.x * 128;
  const int r  = lane & 31;
  const int kg = lane >> 5;

  const float* xA = x + (blk_row0 + w * 32 + r) * 784 + kg * 8;  // wave's A rows

  // stage A of 32-k slab s into A-buf aa (4 gll16/wave, wave-private region)
  #define STAGE_A(aa, s) { _Pragma("unroll") for (int ksl = 0; ksl < 2; ++ksl) { \
      gll16(xA + (s) * 32 + ksl * 16,     &lds[(aa) * 4096 + w * 1024 + ksl * 512]); \
      gll16(xA + (s) * 32 + ksl * 16 + 4, &lds[(aa) * 4096 + w * 1024 + ksl * 512 + 256]); } }
  // tail (16-k, slab 24): 2 gll16/wave
  #define STAGE_AT(aa) {                                                     \
      gll16(xA + 768,     &lds[(aa) * 4096 + w * 1024]);                     \
      gll16(xA + 768 + 4, &lds[(aa) * 4096 + w * 1024 + 256]); }

  // stage B of 32-k slab s into B-buf bb (4 gll16/wave, linear copy)
  #define STAGE_B(bb, s) { _Pragma("unroll") for (int i = 0; i < 4; ++i) {   \
      int j = w * 4 + i;                                                     \
      gll16(wBf + (s) * 4096 + j * 256 + lane * 4,                           \
            &lds[12288 + (bb) * 4096 + j * 256]); } }
  // tail B (16-k): 2 gll16/wave
  #define STAGE_BT(bb) { _Pragma("unroll") for (int i = 0; i < 2; ++i) {     \
      int j = w * 2 + i;                                                     \
      gll16(wBf + 24 * 4096 + j * 256 + lane * 4,                            \
            &lds[12288 + (bb) * 4096 + j * 256]); } }

  // one 16-k step: B frags from B-buf bb (offset ksl), A from A-buf aa
  #define KSTEP(aa, bb, ksl) {                                               \
    f16x8 b[8];                                                              \
    _Pragma("unroll") for (int f = 0; f < 8; ++f)                            \
      b[f] = *(const f16x8*)&lds[12288 + (bb) * 4096 + ((ksl) * 8 + f) * 256 + lane * 4]; \
    fvec4 a0 = *(const fvec4*)&lds[(aa) * 4096 + w * 1024 + (ksl) * 512 + lane * 4]; \
    fvec4 a1 = *(const fvec4*)&lds[(aa) * 4096 + w * 1024 + (ksl) * 512 + 256 + lane * 4]; \
    f16x8 ah, al;                                                            \
    _Pragma("unroll") for (int j = 0; j < 8; ++j) {                          \
      float v = ((j < 4) ? a0[j] : a1[j - 4]) * SX;                          \
      _Float16 hh = (_Float16)v;                                             \
      ah[j] = hh; al[j] = (_Float16)(v - (float)hh);                         \
    }                                                                        \
    _Pragma("unroll") for (int nf = 0; nf < 4; ++nf) {                       \
      acc[nf] = __builtin_amdgcn_mfma_f32_32x32x16_f16(ah, b[nf * 2],     acc[nf], 0, 0, 0); \
      acc[nf] = __builtin_amdgcn_mfma_f32_32x32x16_f16(ah, b[nf * 2 + 1], acc[nf], 0, 0, 0); \
      acc[nf] = __builtin_amdgcn_mfma_f32_32x32x16_f16(al, b[nf * 2],     acc[nf], 0, 0, 0); \
    } }

  #define CPH(aa, bb)  { KSTEP(aa, bb, 0); KSTEP(aa, bb, 1); }

  #define FENCE_A() { __builtin_amdgcn_sched_barrier(0);                     \
    asm volatile("s_waitcnt lgkmcnt(0)" ::: "memory");                       \
    __builtin_amdgcn_s_barrier();                                            \
    asm volatile("" ::: "memory"); }
  #define VMB(vm) {                                                          \
    asm volatile("s_waitcnt vmcnt(" #vm ")" ::: "memory");                   \
    __builtin_amdgcn_s_barrier();                                            \
    asm volatile("" ::: "memory");                                           \
    __builtin_amdgcn_sched_barrier(0); }

  f32x16 acc[4] = {};

  // prologue (issue order matters for in-order vmcnt): A(0), B(0), A(1)
  STAGE_A(0, 0); STAGE_B(0, 0); STAGE_A(1, 1);

  // phase 0: stage B(1)->buf1, A(2)->buf2; wait 12 (A1,B1,A2 may linger)
  FENCE_A(); STAGE_B(1, 1); STAGE_A(2, 2); VMB(12); CPH(0, 0);

  // phases 1..18 (3 groups of 6; all buf indices compile-time)
  for (int g = 0; g < 3; ++g) {
    const int s = 6 * g + 1;
    FENCE_A(); STAGE_B(0, s + 1); STAGE_A(0, s + 2); VMB(12); CPH(1, 1); // s
    FENCE_A(); STAGE_B(1, s + 2); STAGE_A(1, s + 3); VMB(12); CPH(2, 0); // s+1
    FENCE_A(); STAGE_B(0, s + 3); STAGE_A(2, s + 4); VMB(12); CPH(0, 1); // s+2
    FENCE_A(); STAGE_B(1, s + 4); STAGE_A(0, s + 5); VMB(12); CPH(1, 0); // s+3
    FENCE_A(); STAGE_B(0, s + 5); STAGE_A(1, s + 6); VMB(12); CPH(2, 1); // s+4
    FENCE_A(); STAGE_B(1, s + 6); STAGE_A(2, s + 7); VMB(12); CPH(0, 0); // s+5
  }
  // peeled phases 19..24
  FENCE_A(); STAGE_B(0, 20); STAGE_A(0, 21); VMB(12); CPH(1, 1);  // s=19
  FENCE_A(); STAGE_B(1, 21); STAGE_A(1, 22); VMB(12); CPH(2, 0);  // s=20
  FENCE_A(); STAGE_B(0, 22); STAGE_A(2, 23); VMB(12); CPH(0, 1);  // s=21
  FENCE_A(); STAGE_B(1, 23); STAGE_AT(0);    VMB(10); CPH(1, 0);  // s=22 (A24: 2 ops)
  FENCE_A(); STAGE_BT(0);                    VMB(4);  CPH(2, 1);  // s=23 (B24: 2 ops)
  FENCE_A();                                 VMB(0);  KSTEP(0, 0, 0); // s=24 (16-k tail)

  // C/D layout (m74/m101-verified): col = lane&31, row = (reg&3)+8*(reg>>2)+4*(lane>>5)
  float b1v[4];
  #pragma unroll
  for (int nf = 0; nf < 4; ++nf) b1v[nf] = b1[nf * 32 + r];
  long m0 = (long)blockIdx.x * 128 + w * 32;
  #pragma unroll
  for (int nf = 0; nf < 4; ++nf)
    #pragma unroll
    for (int reg = 0; reg < 16; ++reg) {
      int rr = (reg & 3) + 8 * (reg >> 2) + 4 * kg;
      cur1[(m0 + rr) * 128 + nf * 32 + r] = acc[nf][reg] * SINV + b1v[nf];
    }
  #undef STAGE_A
  #undef STAGE_AT
  #undef STAGE_B
  #undef STAGE_BT
  #undef KSTEP
  #undef CPH
  #undef FENCE_A
  #undef VMB
}

// LIF recurrence + layer 2 (bias1 already folded into cur1).
__launch_bounds__(256)
__global__ void lif(const float* __restrict__ cur1,
                    const float* __restrict__ W2,
                    const float* __restrict__ b2,
                    float* __restrict__ out,
                    float* __restrict__ state1,
                    float* __restrict__ state2,
                    int t0, int tn){
  const int lane = threadIdx.x & 63;
  const int b = blockIdx.x * 4 + (threadIdx.x >> 6);
  const int o = lane & 15;
  const int c = lane >> 4;

  float wv[32];
  #pragma unroll
  for (int j = 0; j < 32; ++j) wv[j] = 0.f;
  if (o < 10) {
    #pragma unroll
    for (int j = 0; j < 32; ++j) wv[j] = W2[o * 128 + c * 32 + j];
  }
  float b2v = (lane < 10) ? b2[lane] : 0.f;

  float mem1a, mem1b, mem2;
  if (t0 == 0) { mem1a = 0.f; mem1b = 0.f; mem2 = 0.f; }
  else {
    mem1a = state1[b * 128 + lane];
    mem1b = state1[b * 128 + 64 + lane];
    mem2  = (lane < 10) ? state2[b * 10 + lane] : 0.f;
  }

  for (int t = t0; t < tn; ++t) {
    long base = ((long)(t - t0) * 4096 + b) * 128;
    float c1a = cur1[base + lane];
    float c1b = cur1[base + 64 + lane];
    float r1a = (mem1a > THR) ? THR : 0.f;
    float r1b = (mem1b > THR) ? THR : 0.f;
    mem1a = BETA * mem1a + c1a - r1a;
    mem1b = BETA * mem1b + c1b - r1b;

    uint64_t mA = __ballot(mem1a > THR);
    uint64_t mB = __ballot(mem1b > THR);
    uint64_t m64 = (c & 2) ? mB : mA;
    uint32_t bits = (uint32_t)(m64 >> ((c & 1) << 5));

    float s = 0.f;
    #pragma unroll
    for (int j = 0; j < 32; ++j)
      s = fmaf((float)((bits >> j) & 1u), wv[j], s);   // bfe+cvt+fma
    s += __shfl_xor(s, 16);
    s += __shfl_xor(s, 32);

    if (lane < 10) {
      float cur2 = s + b2v;
      float r2 = (mem2 > THR) ? THR : 0.f;
      mem2 = BETA * mem2 + cur2 - r2;
      float s2 = (mem2 > THR) ? 1.f : 0.f;
      long ob = (long)t * 40960 + (long)b * 10 + lane;
      out[ob] = s2;
      out[1228800 + ob] = mem2;
    }
  }

  if (tn < 30) {
    state1[b * 128 + lane] = mem1a;
    state1[b * 128 + 64 + lane] = mem1b;
    if (lane < 10) state2[b * 10 + lane] = mem2;
  }
}

extern "C" void kernel_launch(void* const* d_in, const int* in_sizes, int n_in,
                              void* d_out, int out_size, void* d_ws, size_t ws_size,
                              hipStream_t stream) {
  const float* x  = (const float*)d_in[0];
  const float* W1 = (const float*)d_in[1];
  const float* b1 = (const float*)d_in[2];
  const float* W2 = (const float*)d_in[3];
  const float* b2 = (const float*)d_in[4];
  float* out = (float*)d_out;

  const int T = 30, B = 4096;

  char* ws = (char*)d_ws;
  _Float16* wB = (_Float16*)ws;                  // 49*8*512 fp16 = 392KB
  size_t off = (size_t)49 * 8 * 512 * sizeof(_Float16);
  off = (off + 255) & ~(size_t)255;
  float* state1 = (float*)(ws + off); off += (size_t)B * 128 * 4;
  float* state2 = (float*)(ws + off); off += (size_t)B * 10 * 4;
  off = (off + 255) & ~(size_t)255;
  float* cur1 = (float*)(ws + off);

  size_t per_t = (size_t)B * 128 * 4;
  size_t avail = (ws_size > off) ? (ws_size - off) : 0;
  int CH = (int)(avail / per_t);
  if (CH > T) CH = T;
  if (CH < 1) CH = 1;

  split_w1<<<(W1N + 255) / 256, 256, 0, stream>>>(W1, wB);

  for (int t0 = 0; t0 < T; t0 += CH) {
    int tn = (t0 + CH < T) ? (t0 + CH) : T;
    int mrows = (tn - t0) * B;                   // multiple of 4096 -> multiple of 128
    gemm1<<<mrows / 128, 256, 0, stream>>>(x, (const float*)wB, b1, cur1, (long)t0 * B);
    lif<<<B / 4, 256, 0, stream>>>(cur1, W2, b2, out, state1, state2, t0, tn);
  }
}